// Round 1
// baseline (5064.775 us; speedup 1.0000x reference)
//
#include <hip/hip_runtime.h>

constexpr int BT  = 32;    // batch tile per workgroup
constexpr int HID = 256;   // hidden width
constexpr int NS  = 7;     // states
constexpr int NC  = 2;     // controls
constexpr int NF  = 9;     // NC + NS
constexpr int HS  = 50;    // horizon
constexpr float DT_C = 0.02f;

__device__ __forceinline__ float fast_tanh(float x) {
    // tanh(x) = 1 - 2/(exp(2x)+1); handles +-inf correctly (-> +-1)
    float e = __expf(2.0f * x);
    return 1.0f - 2.0f / (e + 1.0f);
}

__global__ __launch_bounds__(256, 2)
void rollout_f32(const float* __restrict__ x,
                 const float* __restrict__ W1, const float* __restrict__ b1,
                 const float* __restrict__ W2, const float* __restrict__ b2,
                 const float* __restrict__ W3, const float* __restrict__ b3,
                 float* __restrict__ out)
{
    __shared__ float ni[BT][NF];        // [u0,u1,state0..6] per batch row
    __shared__ float h1[BT][HID];       // 16B-aligned rows for float4 reads
    __shared__ float h2[BT][HID + 1];   // +1 pad: D-phase reads hit all 32 banks
    __shared__ float w3s[HID * NS];
    __shared__ float b3s[NS];

    const int tid = threadIdx.x;
    const int b0  = blockIdx.x * BT;

    // Thread tid owns hidden column tid: hoist W1 column + biases to registers.
    float w1r[NF];
    #pragma unroll
    for (int k = 0; k < NF; ++k) w1r[k] = W1[k * HID + tid];
    const float b1r = b1[tid];
    const float b2r = b2[tid];

    // Stage W3/b3 into LDS once.
    for (int i = tid; i < HID * NS; i += 256) w3s[i] = W3[i];
    if (tid < NS) b3s[tid] = b3[tid];

    // Initial state: x[:,0,2:9]
    if (tid < BT * NS) {
        int b = tid / NS, s = tid % NS;
        ni[b][NC + s] = x[(b0 + b) * (HS * NF) + NC + s];
    }
    // Controls for t=0
    if (tid < BT * NC) {
        int b = tid >> 1, c = tid & 1;
        ni[b][c] = x[(b0 + b) * (HS * NF) + c];
    }
    __syncthreads();

    for (int t = 0; t < HS; ++t) {
        // ---- h1 = tanh(ni @ W1 + b1): thread j computes h1[b][j] for all b
        #pragma unroll 8
        for (int b = 0; b < BT; ++b) {
            float a = b1r;
            #pragma unroll
            for (int k = 0; k < NF; ++k) a = fmaf(ni[b][k], w1r[k], a);
            h1[b][tid] = fast_tanh(a);
        }
        __syncthreads();

        // ---- h2 = tanh(h1 @ W2 + b2): thread j accumulates column j for all b
        float acc[BT];
        #pragma unroll
        for (int b = 0; b < BT; ++b) acc[b] = b2r;

        for (int kq = 0; kq < HID / 4; ++kq) {
            const float* w2p = &W2[(4 * kq) * HID + tid];   // coalesced rows
            float wa = w2p[0];
            float wb = w2p[HID];
            float wc = w2p[2 * HID];
            float wd = w2p[3 * HID];
            #pragma unroll
            for (int b = 0; b < BT; ++b) {
                float4 hv = *reinterpret_cast<const float4*>(&h1[b][4 * kq]); // broadcast
                float a = acc[b];
                a = fmaf(hv.x, wa, a);
                a = fmaf(hv.y, wb, a);
                a = fmaf(hv.z, wc, a);
                a = fmaf(hv.w, wd, a);
                acc[b] = a;
            }
        }
        #pragma unroll
        for (int b = 0; b < BT; ++b) h2[b][tid] = fast_tanh(acc[b]);
        __syncthreads();

        // ---- d_state = h2 @ W3 + b3; state += DT*d; write out. 224 threads.
        if (tid < BT * NS) {
            int b = tid / NS, s = tid % NS;
            float a = b3s[s];
            #pragma unroll 8
            for (int k = 0; k < HID; ++k)
                a = fmaf(h2[b][k], w3s[k * NS + s], a);
            float nsv = ni[b][NC + s] + DT_C * a;
            ni[b][NC + s] = nsv;
            out[(b0 + b) * (HS * NS) + t * NS + s] = nsv;
        } else if (tid >= 256 - BT) {
            // remaining threads prefetch controls for t+1
            int b = tid - (256 - BT);
            if (t + 1 < HS) {
                const float* xp = &x[(b0 + b) * (HS * NF) + (t + 1) * NF];
                ni[b][0] = xp[0];
                ni[b][1] = xp[1];
            }
        }
        __syncthreads();
    }
}

extern "C" void kernel_launch(void* const* d_in, const int* in_sizes, int n_in,
                              void* d_out, int out_size, void* d_ws, size_t ws_size,
                              hipStream_t stream) {
    const float* x  = (const float*)d_in[0];
    const float* W1 = (const float*)d_in[1];
    const float* b1 = (const float*)d_in[2];
    const float* W2 = (const float*)d_in[3];
    const float* b2 = (const float*)d_in[4];
    const float* W3 = (const float*)d_in[5];
    const float* b3 = (const float*)d_in[6];
    float* out = (float*)d_out;

    const int B = in_sizes[0] / (HS * NF);   // 32768
    dim3 grid(B / BT), block(256);
    hipLaunchKernelGGL(rollout_f32, grid, block, 0, stream,
                       x, W1, b1, W2, b2, W3, b3, out);
}

// Round 2
// 3749.659 us; speedup vs baseline: 1.3507x; 1.3507x over previous
//
#include <hip/hip_runtime.h>

constexpr int BT  = 64;    // batch tile per workgroup
constexpr int HID = 256;   // hidden width
constexpr int NS  = 7;     // states
constexpr int NC  = 2;     // controls
constexpr int NF  = 9;     // NC + NS
constexpr int HS  = 50;    // horizon
constexpr int H1P = 260;   // padded hidden row (floats): 1040 B, 16B-aligned, bank-spread
constexpr float DT_C = 0.02f;

__device__ __forceinline__ float fast_tanh(float x) {
    // tanh(x) = 1 - 2/(exp(2x)+1); handles +-inf correctly (-> +-1)
    float e = __expf(2.0f * x);
    return 1.0f - 2.0f / (e + 1.0f);
}

__global__ __launch_bounds__(256, 2)
void rollout_f32(const float* __restrict__ x,
                 const float* __restrict__ W1, const float* __restrict__ b1,
                 const float* __restrict__ W2, const float* __restrict__ b2,
                 const float* __restrict__ W3, const float* __restrict__ b3,
                 float* __restrict__ out)
{
    // hbuf holds h1, then is reused for h2 (saves 66 KB -> keeps 2 blocks/CU)
    __shared__ float hbuf[BT][H1P];
    __shared__ float ni[BT][12];        // [u0,u1,state0..6,pad...] 48B rows
    __shared__ float w3t[NS][H1P];      // transposed W3, padded rows
    __shared__ float b3s[NS];

    const int tid   = threadIdx.x;
    const int b0    = blockIdx.x * BT;
    const int wave  = tid >> 6;
    const int lane  = tid & 63;
    const int bbase = (wave >> 1) * 32;           // waves 0,1 -> b 0..31; 2,3 -> 32..63
    const int j0    = (wave & 1) * 128 + lane * 2; // two adjacent hidden columns

    // Hoist this thread's two W1 columns + biases into registers.
    float w1r[NF][2];
    #pragma unroll
    for (int k = 0; k < NF; ++k) {
        w1r[k][0] = W1[k * HID + j0];
        w1r[k][1] = W1[k * HID + j0 + 1];
    }
    const float b1x = b1[j0], b1y = b1[j0 + 1];
    const float b2x = b2[j0], b2y = b2[j0 + 1];

    // Stage W3^T (padded) and b3 into LDS once.
    for (int i = tid; i < HID * NS; i += 256) {
        int k = i / NS, s = i - k * NS;
        w3t[s][k] = W3[i];
    }
    if (tid < NS) b3s[tid] = b3[tid];

    // Init net-in rows: controls(t=0) + state0 = x[b][0][0..8]
    if (tid < BT) {
        const float* xp = &x[(b0 + tid) * (HS * NF)];
        #pragma unroll
        for (int f = 0; f < NF; ++f) ni[tid][f] = xp[f];
    }
    __syncthreads();

    const int brow = tid / 7;           // phase-3 mapping (threads 0..223)
    const int srow = tid - brow * 7;

    for (int t = 0; t < HS; ++t) {
        // ---- phase 1: h1 = tanh(ni @ W1 + b1); thread covers (j0,j0+1) x 32 b
        #pragma unroll 4
        for (int bi = 0; bi < 32; ++bi) {
            const int b = bbase + bi;
            float4 q0 = *reinterpret_cast<const float4*>(&ni[b][0]);
            float4 q1 = *reinterpret_cast<const float4*>(&ni[b][4]);
            float  n8 = ni[b][8];
            float nv[NF] = {q0.x, q0.y, q0.z, q0.w, q1.x, q1.y, q1.z, q1.w, n8};
            float a0 = b1x, a1 = b1y;
            #pragma unroll
            for (int k = 0; k < NF; ++k) {
                a0 = fmaf(nv[k], w1r[k][0], a0);
                a1 = fmaf(nv[k], w1r[k][1], a1);
            }
            float2 hv = {fast_tanh(a0), fast_tanh(a1)};
            *reinterpret_cast<float2*>(&hbuf[b][j0]) = hv;
        }
        __syncthreads();

        // ---- phase 2: h2 = tanh(h1 @ W2 + b2); 8 FMA per b128 broadcast read
        float acc0[32], acc1[32];
        #pragma unroll
        for (int bi = 0; bi < 32; ++bi) { acc0[bi] = b2x; acc1[bi] = b2y; }

        for (int kq = 0; kq < HID / 4; ++kq) {
            const float* w2p = &W2[(4 * kq) * HID + j0];
            float2 wA = *reinterpret_cast<const float2*>(w2p);
            float2 wB = *reinterpret_cast<const float2*>(w2p + HID);
            float2 wC = *reinterpret_cast<const float2*>(w2p + 2 * HID);
            float2 wD = *reinterpret_cast<const float2*>(w2p + 3 * HID);
            #pragma unroll
            for (int bi = 0; bi < 32; ++bi) {
                float4 hv = *reinterpret_cast<const float4*>(&hbuf[bbase + bi][4 * kq]);
                float a0 = acc0[bi], a1 = acc1[bi];
                a0 = fmaf(hv.x, wA.x, a0);  a1 = fmaf(hv.x, wA.y, a1);
                a0 = fmaf(hv.y, wB.x, a0);  a1 = fmaf(hv.y, wB.y, a1);
                a0 = fmaf(hv.z, wC.x, a0);  a1 = fmaf(hv.z, wC.y, a1);
                a0 = fmaf(hv.w, wD.x, a0);  a1 = fmaf(hv.w, wD.y, a1);
                acc0[bi] = a0; acc1[bi] = a1;
            }
        }
        __syncthreads();   // all h1 reads done before overwrite

        #pragma unroll 8
        for (int bi = 0; bi < 32; ++bi) {
            float2 hv = {fast_tanh(acc0[bi]), fast_tanh(acc1[bi])};
            *reinterpret_cast<float2*>(&hbuf[bbase + bi][j0]) = hv;
        }
        __syncthreads();   // h2 visible

        // ---- phase 3: d = h2 @ W3 + b3; state += DT*d; write out
        if (tid < 224) {
            #pragma unroll
            for (int bb = 0; bb < 2; ++bb) {
                const int b = bb * 32 + brow;
                float a = b3s[srow];
                #pragma unroll 8
                for (int kq = 0; kq < HID / 4; ++kq) {
                    float4 hv = *reinterpret_cast<const float4*>(&hbuf[b][4 * kq]);
                    float4 wv = *reinterpret_cast<const float4*>(&w3t[srow][4 * kq]);
                    a = fmaf(hv.x, wv.x, a);
                    a = fmaf(hv.y, wv.y, a);
                    a = fmaf(hv.z, wv.z, a);
                    a = fmaf(hv.w, wv.w, a);
                }
                float nsv = ni[b][NC + srow] + DT_C * a;
                ni[b][NC + srow] = nsv;
                out[(b0 + b) * (HS * NS) + t * NS + srow] = nsv;
            }
        } else {
            // threads 224..255 prefetch next controls for b = th and th+32
            const int th = tid - 224;
            if (t + 1 < HS) {
                #pragma unroll
                for (int bb = 0; bb < 2; ++bb) {
                    const int b = bb * 32 + th;
                    const float* xp = &x[(b0 + b) * (HS * NF) + (t + 1) * NF];
                    ni[b][0] = xp[0];
                    ni[b][1] = xp[1];
                }
            }
        }
        __syncthreads();
    }
}

extern "C" void kernel_launch(void* const* d_in, const int* in_sizes, int n_in,
                              void* d_out, int out_size, void* d_ws, size_t ws_size,
                              hipStream_t stream) {
    const float* x  = (const float*)d_in[0];
    const float* W1 = (const float*)d_in[1];
    const float* b1 = (const float*)d_in[2];
    const float* W2 = (const float*)d_in[3];
    const float* b2 = (const float*)d_in[4];
    const float* W3 = (const float*)d_in[5];
    const float* b3 = (const float*)d_in[6];
    float* out = (float*)d_out;

    const int B = in_sizes[0] / (HS * NF);   // 32768
    dim3 grid(B / BT), block(256);
    hipLaunchKernelGGL(rollout_f32, grid, block, 0, stream,
                       x, W1, b1, W2, b2, W3, b3, out);
}

// Round 3
// 804.243 us; speedup vs baseline: 6.2976x; 4.6623x over previous
//
#include <hip/hip_runtime.h>

constexpr int HID = 256;
constexpr int NS = 7, NC = 2, NF = 9, HS = 50;
constexpr int BT = 32;                // batch rows per block
constexpr int ROW = 264;              // padded bf16 row pitch (528 B)
constexpr float DT_C = 0.02f;

using short8 = __attribute__((ext_vector_type(8))) short;
using f32x4  = __attribute__((ext_vector_type(4))) float;

__device__ __forceinline__ unsigned short f2bf(float f) {
    unsigned int u = __float_as_uint(f);
    return (unsigned short)((u + 0x7FFFu + ((u >> 16) & 1u)) >> 16);   // RNE
}
__device__ __forceinline__ float fast_tanh(float x) {
    float e = __expf(2.0f * x);
    return 1.0f - 2.0f / (e + 1.0f);
}

__global__ __launch_bounds__(256, 2)
void rollout_mfma(const float* __restrict__ x,
                  const float* __restrict__ W1, const float* __restrict__ b1,
                  const float* __restrict__ W2, const float* __restrict__ b2,
                  const float* __restrict__ W3, const float* __restrict__ b3,
                  float* __restrict__ out)
{
    __shared__ __align__(16) unsigned short hbuf[BT][ROW];  // h1, then h2 (bf16)
    __shared__ __align__(16) unsigned short w3t[16][ROW];   // W3^T, cols>=7 zero
    __shared__ float ni[BT][12];                            // [u0,u1,s0..6,pad]

    const int tid  = threadIdx.x;
    const int w    = tid >> 6;        // wave 0..3
    const int lane = tid & 63;
    const int l15  = lane & 15;
    const int lg   = lane >> 4;
    const int b0   = blockIdx.x * BT;

    // ---- one-time: W2^T A-fragments in registers ----
    // frag(q,kb): lane holds W2[k = kb*32+lg*8+j][n = w*64+q*16+l15]
    short8 w2f[4][8];
    #pragma unroll
    for (int q = 0; q < 4; ++q) {
        const int n = w * 64 + q * 16 + l15;
        #pragma unroll
        for (int kb = 0; kb < 8; ++kb) {
            #pragma unroll
            for (int j = 0; j < 8; ++j)
                w2f[q][kb][j] = (short)f2bf(W2[(kb * 32 + lg * 8 + j) * HID + n]);
        }
    }
    // bias for P2 outputs: element r of tile q sits at n = w*64+q*16+lg*4+r
    f32x4 b2v[4];
    #pragma unroll
    for (int q = 0; q < 4; ++q)
        #pragma unroll
        for (int r = 0; r < 4; ++r)
            b2v[q][r] = b2[w * 64 + q * 16 + lg * 4 + r];

    float b3r[4];
    #pragma unroll
    for (int r = 0; r < 4; ++r) {
        const int s = lg * 4 + r;
        b3r[r] = (s < NS) ? b3[s] : 0.0f;
    }

    // P1 mapping: two adjacent hidden cols, half the batch rows
    const int c2 = (tid & 127) * 2;
    const int bh = (tid >> 7) * 16;
    float w1a[NF], w1b[NF];
    #pragma unroll
    for (int k = 0; k < NF; ++k) {
        w1a[k] = W1[k * HID + c2];
        w1b[k] = W1[k * HID + c2 + 1];
    }
    const float b1a = b1[c2], b1b = b1[c2 + 1];

    // stage W3^T (bf16, zero-padded cols) into LDS
    for (int i = tid; i < 16 * HID; i += 256) {
        const int s = i & 15, k = i >> 4;
        w3t[s][k] = (s < NS) ? f2bf(W3[k * NS + s]) : (unsigned short)0;
    }
    // initial net-in: x[b][0][0..8]
    if (tid < BT) {
        const float* xp = &x[(b0 + tid) * (HS * NF)];
        #pragma unroll
        for (int f = 0; f < NF; ++f) ni[tid][f] = xp[f];
    }
    __syncthreads();

    for (int t = 0; t < HS; ++t) {
        // ---------- P1: h1 = tanh(ni @ W1 + b1)  (fp32 VALU) ----------
        #pragma unroll 4
        for (int bi = 0; bi < 16; ++bi) {
            const int b = bh + bi;
            float4 q0 = *reinterpret_cast<const float4*>(&ni[b][0]);
            float4 q1 = *reinterpret_cast<const float4*>(&ni[b][4]);
            float  n8 = ni[b][8];
            float nv[NF] = {q0.x, q0.y, q0.z, q0.w, q1.x, q1.y, q1.z, q1.w, n8};
            float a0 = b1a, a1 = b1b;
            #pragma unroll
            for (int k = 0; k < NF; ++k) {
                a0 = fmaf(nv[k], w1a[k], a0);
                a1 = fmaf(nv[k], w1b[k], a1);
            }
            unsigned int pk = (unsigned int)f2bf(fast_tanh(a0))
                            | ((unsigned int)f2bf(fast_tanh(a1)) << 16);
            *reinterpret_cast<unsigned int*>(&hbuf[b][c2]) = pk;
        }
        __syncthreads();

        // ---------- P2: h2 = tanh(h1 @ W2 + b2)  (MFMA) ----------
        // D[n][b]: A = W2^T tile (regs), B = h1 rows (LDS, row-major = B^T)
        f32x4 acc[4][2];
        #pragma unroll
        for (int q = 0; q < 4; ++q) { acc[q][0] = b2v[q]; acc[q][1] = b2v[q]; }
        #pragma unroll
        for (int kb = 0; kb < 8; ++kb) {
            short8 hA = *reinterpret_cast<const short8*>(&hbuf[l15][kb * 32 + lg * 8]);
            short8 hB = *reinterpret_cast<const short8*>(&hbuf[16 + l15][kb * 32 + lg * 8]);
            #pragma unroll
            for (int q = 0; q < 4; ++q) {
                acc[q][0] = __builtin_amdgcn_mfma_f32_16x16x32_bf16(w2f[q][kb], hA, acc[q][0], 0, 0, 0);
                acc[q][1] = __builtin_amdgcn_mfma_f32_16x16x32_bf16(w2f[q][kb], hB, acc[q][1], 0, 0, 0);
            }
        }
        __syncthreads();   // every wave done reading h1 before overwrite

        // lane element r of tile (q,bt): b = bt*16+l15, n = w*64+q*16+lg*4+r
        #pragma unroll
        for (int q = 0; q < 4; ++q) {
            #pragma unroll
            for (int bt = 0; bt < 2; ++bt) {
                unsigned int lo = (unsigned int)f2bf(fast_tanh(acc[q][bt][0]))
                                | ((unsigned int)f2bf(fast_tanh(acc[q][bt][1])) << 16);
                unsigned int hi = (unsigned int)f2bf(fast_tanh(acc[q][bt][2]))
                                | ((unsigned int)f2bf(fast_tanh(acc[q][bt][3])) << 16);
                uint2 pk; pk.x = lo; pk.y = hi;
                *reinterpret_cast<uint2*>(&hbuf[bt * 16 + l15][w * 64 + q * 16 + lg * 4]) = pk;
            }
        }
        __syncthreads();

        // ---------- P3: d = h2 @ W3 + b3; state update (waves 0,1) ----------
        if (w < 2) {
            f32x4 a3 = {0.f, 0.f, 0.f, 0.f};
            #pragma unroll
            for (int kb = 0; kb < 8; ++kb) {
                short8 hv = *reinterpret_cast<const short8*>(&hbuf[w * 16 + l15][kb * 32 + lg * 8]);
                short8 wf = *reinterpret_cast<const short8*>(&w3t[l15][kb * 32 + lg * 8]);
                a3 = __builtin_amdgcn_mfma_f32_16x16x32_bf16(wf, hv, a3, 0, 0, 0);
            }
            const int b = w * 16 + l15;                // D: s = lg*4+r, b = l15
            #pragma unroll
            for (int r = 0; r < 4; ++r) {
                const int s = lg * 4 + r;
                if (s < NS) {
                    float nsv = ni[b][NC + s] + DT_C * (a3[r] + b3r[r]);
                    ni[b][NC + s] = nsv;
                    out[(b0 + b) * (HS * NS) + t * NS + s] = nsv;
                }
            }
        } else if (w == 2) {
            // wave 2: fetch next-step controls into ni[b][0..1]
            if (t + 1 < HS) {
                const int b = lane & 31, c = lane >> 5;
                ni[b][c] = x[(b0 + b) * (HS * NF) + (t + 1) * NF + c];
            }
        }
        __syncthreads();
    }
}

extern "C" void kernel_launch(void* const* d_in, const int* in_sizes, int n_in,
                              void* d_out, int out_size, void* d_ws, size_t ws_size,
                              hipStream_t stream) {
    const float* x  = (const float*)d_in[0];
    const float* W1 = (const float*)d_in[1];
    const float* b1 = (const float*)d_in[2];
    const float* W2 = (const float*)d_in[3];
    const float* b2 = (const float*)d_in[4];
    const float* W3 = (const float*)d_in[5];
    const float* b3 = (const float*)d_in[6];
    float* out = (float*)d_out;

    const int B = in_sizes[0] / (HS * NF);   // 32768
    dim3 grid(B / BT), block(256);
    hipLaunchKernelGGL(rollout_mfma, grid, block, 0, stream,
                       x, W1, b1, W2, b2, W3, b3, out);
}

// Round 4
// 603.999 us; speedup vs baseline: 8.3854x; 1.3315x over previous
//
#include <hip/hip_runtime.h>

constexpr int HID = 256;
constexpr int NS = 7, NC = 2, NF = 9, HS = 50;
constexpr int BT  = 32;    // batch rows per block
constexpr int ROW = 264;   // bf16 row pitch for h buffers / w3t (528 B)
constexpr int NIP = 40;    // ni_bf row pitch in shorts (80 B, 16B-aligned)
constexpr float DT_C = 0.02f;

using short8 = __attribute__((ext_vector_type(8))) short;
using f32x4  = __attribute__((ext_vector_type(4))) float;

__device__ __forceinline__ unsigned short f2bf(float f) {
    unsigned int u = __float_as_uint(f);
    return (unsigned short)((u + 0x7FFFu + ((u >> 16) & 1u)) >> 16);   // RNE
}
__device__ __forceinline__ unsigned int cvt_pk_bf16(float lo, float hi) {
    unsigned int r;
    asm("v_cvt_pk_bf16_f32 %0, %1, %2" : "=v"(r) : "v"(lo), "v"(hi));
    return r;
}
__device__ __forceinline__ float fast_tanh(float x) {
    float e = __expf(2.0f * x);
    return 1.0f - 2.0f / (e + 1.0f);
}

__global__ __launch_bounds__(256, 2)
void rollout_mfma2(const float* __restrict__ x,
                   const float* __restrict__ W1, const float* __restrict__ b1,
                   const float* __restrict__ W2, const float* __restrict__ b2,
                   const float* __restrict__ W3, const float* __restrict__ b3,
                   float* __restrict__ out)
{
    __shared__ __align__(16) unsigned short hA[BT][ROW];    // h1
    __shared__ __align__(16) unsigned short hB[BT][ROW];    // h2
    __shared__ __align__(16) unsigned short w3t[16][ROW];   // W3^T, cols>=7 zero
    __shared__ __align__(16) unsigned short nibf[BT][NIP];  // [u0,u1,s0..6,1.0,0...]
    __shared__ __align__(16) float b2s[HID];

    const int tid  = threadIdx.x;
    const int w    = tid >> 6;
    const int lane = tid & 63;
    const int l15  = lane & 15;
    const int lg   = lane >> 4;
    const int b0   = blockIdx.x * BT;

    // ---- one-time: W2^T A-fragments (k = kb*32+lg*8+j, n = w*64+q*16+l15) ----
    short8 w2f[4][8];
    #pragma unroll
    for (int q = 0; q < 4; ++q) {
        const int n = w * 64 + q * 16 + l15;
        #pragma unroll
        for (int kb = 0; kb < 8; ++kb)
            #pragma unroll
            for (int j = 0; j < 8; ++j)
                w2f[q][kb][j] = (short)f2bf(W2[(kb * 32 + lg * 8 + j) * HID + n]);
    }
    // W1' A-fragments: rows 0..8 = W1, row 9 = b1 (bias via k), rows 10..31 = 0
    short8 w1f[4];
    #pragma unroll
    for (int q = 0; q < 4; ++q) {
        const int n = w * 64 + q * 16 + l15;
        #pragma unroll
        for (int j = 0; j < 8; ++j) {
            const int k = lg * 8 + j;
            float v = (k < NF) ? W1[k * HID + n] : (k == NF ? b1[n] : 0.0f);
            w1f[q][j] = (short)f2bf(v);
        }
    }
    float b3r[4];
    #pragma unroll
    for (int r = 0; r < 4; ++r) {
        const int s = lg * 4 + r;
        b3r[r] = (s < NS) ? b3[s] : 0.0f;
    }
    for (int i = tid; i < HID; i += 256) b2s[i] = b2[i];
    for (int i = tid; i < 16 * HID; i += 256) {
        const int s = i & 15, k = i >> 4;
        w3t[s][k] = (s < NS) ? f2bf(W3[k * NS + s]) : (unsigned short)0;
    }
    // net-in rows: x[b][0][0..8], bias-one at k=9, zeros above
    if (tid < BT) {
        const float* xp = &x[(b0 + tid) * (HS * NF)];
        #pragma unroll
        for (int k = 0; k < NIP; ++k) nibf[tid][k] = 0;
        #pragma unroll
        for (int f = 0; f < NF; ++f) nibf[tid][f] = f2bf(xp[f]);
        nibf[tid][NF] = f2bf(1.0f);
    }
    // master state in registers of waves 0,1: lane (l15,lg) owns b=w*16+l15, s=lg*4+r
    float st[4] = {0.f, 0.f, 0.f, 0.f};
    if (w < 2) {
        const int b = w * 16 + l15;
        #pragma unroll
        for (int r = 0; r < 4; ++r) {
            const int s = lg * 4 + r;
            if (s < NS) st[r] = x[(b0 + b) * (HS * NF) + NC + s];
        }
    }
    __syncthreads();

    for (int t = 0; t < HS; ++t) {
        // ---------- P1: h1 = tanh([ni,1] @ W1') via MFMA ----------
        f32x4 a1[4][2];
        #pragma unroll
        for (int q = 0; q < 4; ++q) { a1[q][0] = {0,0,0,0}; a1[q][1] = {0,0,0,0}; }
        #pragma unroll
        for (int bt = 0; bt < 2; ++bt) {
            short8 nf = *reinterpret_cast<const short8*>(&nibf[bt * 16 + l15][lg * 8]);
            #pragma unroll
            for (int q = 0; q < 4; ++q)
                a1[q][bt] = __builtin_amdgcn_mfma_f32_16x16x32_bf16(w1f[q], nf, a1[q][bt], 0, 0, 0);
        }
        #pragma unroll
        for (int q = 0; q < 4; ++q)
            #pragma unroll
            for (int bt = 0; bt < 2; ++bt) {
                unsigned int lo = cvt_pk_bf16(fast_tanh(a1[q][bt][0]), fast_tanh(a1[q][bt][1]));
                unsigned int hi = cvt_pk_bf16(fast_tanh(a1[q][bt][2]), fast_tanh(a1[q][bt][3]));
                uint2 pk; pk.x = lo; pk.y = hi;
                *reinterpret_cast<uint2*>(&hA[bt * 16 + l15][w * 64 + q * 16 + lg * 4]) = pk;
            }
        __syncthreads();   // S1: h1 ready

        // ---------- P2: h2 = tanh(h1 @ W2 + b2) via MFMA ----------
        f32x4 acc[4][2];
        #pragma unroll
        for (int q = 0; q < 4; ++q) { acc[q][0] = {0,0,0,0}; acc[q][1] = {0,0,0,0}; }
        #pragma unroll
        for (int kb = 0; kb < 8; ++kb) {
            short8 h0 = *reinterpret_cast<const short8*>(&hA[l15][kb * 32 + lg * 8]);
            short8 h1v = *reinterpret_cast<const short8*>(&hA[16 + l15][kb * 32 + lg * 8]);
            #pragma unroll
            for (int q = 0; q < 4; ++q) {
                acc[q][0] = __builtin_amdgcn_mfma_f32_16x16x32_bf16(w2f[q][kb], h0, acc[q][0], 0, 0, 0);
                acc[q][1] = __builtin_amdgcn_mfma_f32_16x16x32_bf16(w2f[q][kb], h1v, acc[q][1], 0, 0, 0);
            }
        }
        #pragma unroll
        for (int q = 0; q < 4; ++q) {
            const float4 bv = *reinterpret_cast<const float4*>(&b2s[w * 64 + q * 16 + lg * 4]);
            #pragma unroll
            for (int bt = 0; bt < 2; ++bt) {
                unsigned int lo = cvt_pk_bf16(fast_tanh(acc[q][bt][0] + bv.x),
                                              fast_tanh(acc[q][bt][1] + bv.y));
                unsigned int hi = cvt_pk_bf16(fast_tanh(acc[q][bt][2] + bv.z),
                                              fast_tanh(acc[q][bt][3] + bv.w));
                uint2 pk; pk.x = lo; pk.y = hi;
                *reinterpret_cast<uint2*>(&hB[bt * 16 + l15][w * 64 + q * 16 + lg * 4]) = pk;
            }
        }
        __syncthreads();   // S2: h2 ready, h1 free

        // ---------- P3: d = h2 @ W3 + b3; state += DT*d ----------
        if (w < 2) {
            f32x4 a3 = {0.f, 0.f, 0.f, 0.f};
            #pragma unroll
            for (int kb = 0; kb < 8; ++kb) {
                short8 hv = *reinterpret_cast<const short8*>(&hB[w * 16 + l15][kb * 32 + lg * 8]);
                short8 wf = *reinterpret_cast<const short8*>(&w3t[l15][kb * 32 + lg * 8]);
                a3 = __builtin_amdgcn_mfma_f32_16x16x32_bf16(wf, hv, a3, 0, 0, 0);
            }
            const int b = w * 16 + l15;
            #pragma unroll
            for (int r = 0; r < 4; ++r) {
                const int s = lg * 4 + r;
                if (s < NS) {
                    float nsv = st[r] + DT_C * (a3[r] + b3r[r]);
                    st[r] = nsv;
                    nibf[b][NC + s] = f2bf(nsv);
                    out[(b0 + b) * (HS * NS) + t * NS + s] = nsv;
                }
            }
        } else if (w == 2) {
            // next-step controls -> nibf[b][0..1] (bf16)
            if (t + 1 < HS) {
                const int b = lane & 31, c = lane >> 5;
                nibf[b][c] = f2bf(x[(b0 + b) * (HS * NF) + (t + 1) * NF + c]);
            }
        }
        __syncthreads();   // S3: state/controls ready for next P1
    }
}

extern "C" void kernel_launch(void* const* d_in, const int* in_sizes, int n_in,
                              void* d_out, int out_size, void* d_ws, size_t ws_size,
                              hipStream_t stream) {
    const float* x  = (const float*)d_in[0];
    const float* W1 = (const float*)d_in[1];
    const float* b1 = (const float*)d_in[2];
    const float* W2 = (const float*)d_in[3];
    const float* b2 = (const float*)d_in[4];
    const float* W3 = (const float*)d_in[5];
    const float* b3 = (const float*)d_in[6];
    float* out = (float*)d_out;

    const int B = in_sizes[0] / (HS * NF);   // 32768
    dim3 grid(B / BT), block(256);
    hipLaunchKernelGGL(rollout_mfma2, grid, block, 0, stream,
                       x, W1, b1, W2, b2, W3, b3, out);
}

// Round 5
// 591.548 us; speedup vs baseline: 8.5619x; 1.0210x over previous
//
#include <hip/hip_runtime.h>

constexpr int HID = 256;
constexpr int NS = 7, NC = 2, NF = 9, HS = 50;
constexpr int BT  = 32;    // batch rows per block
constexpr int ROW = 264;   // bf16 row pitch for h buffers / w3t (528 B)
constexpr int NIP = 40;    // ni_bf row pitch in shorts (80 B, 16B-aligned)
constexpr float DT_C = 0.02f;

using short8 = __attribute__((ext_vector_type(8))) short;
using f32x4  = __attribute__((ext_vector_type(4))) float;

__device__ __forceinline__ unsigned short f2bf(float f) {
    unsigned int u = __float_as_uint(f);
    return (unsigned short)((u + 0x7FFFu + ((u >> 16) & 1u)) >> 16);   // RNE
}
__device__ __forceinline__ unsigned int cvt_pk_bf16(float lo, float hi) {
    unsigned int r;
    asm("v_cvt_pk_bf16_f32 %0, %1, %2" : "=v"(r) : "v"(lo), "v"(hi));
    return r;
}
__device__ __forceinline__ float fast_tanh(float x) {
    // 1 - 2/(e^{2x}+1) with fast rcp (v_rcp_f32): ~7 VALU ops, 2 trans.
    // inf-safe: e=inf -> rcp -> 0 -> 1; e=0 -> 1-2 = -1.
    float e = __expf(2.0f * x);
    return 1.0f - __fdividef(2.0f, e + 1.0f);
}

__global__ __launch_bounds__(256, 2)
void rollout_mfma3(const float* __restrict__ x,
                   const float* __restrict__ W1, const float* __restrict__ b1,
                   const float* __restrict__ W2, const float* __restrict__ b2,
                   const float* __restrict__ W3, const float* __restrict__ b3,
                   float* __restrict__ out)
{
    __shared__ __align__(16) unsigned short hA[BT][ROW];    // h1
    __shared__ __align__(16) unsigned short hB[BT][ROW];    // h2
    __shared__ __align__(16) unsigned short w3t[16][ROW];   // W3^T, cols>=7 zero
    __shared__ __align__(16) unsigned short nibf[BT][NIP];  // [u0,u1,s0..6,1.0,0...]
    __shared__ __align__(16) float b2s[HID];

    const int tid  = threadIdx.x;
    const int w    = tid >> 6;
    const int lane = tid & 63;
    const int l15  = lane & 15;
    const int lg   = lane >> 4;
    const int b0   = blockIdx.x * BT;

    // ---- one-time: W2^T A-fragments (k = kb*32+lg*8+j, n = w*64+q*16+l15) ----
    short8 w2f[4][8];
    #pragma unroll
    for (int q = 0; q < 4; ++q) {
        const int n = w * 64 + q * 16 + l15;
        #pragma unroll
        for (int kb = 0; kb < 8; ++kb)
            #pragma unroll
            for (int j = 0; j < 8; ++j)
                w2f[q][kb][j] = (short)f2bf(W2[(kb * 32 + lg * 8 + j) * HID + n]);
    }
    // W1' A-fragments: rows 0..8 = W1, row 9 = b1 (bias via k), rows 10..31 = 0
    short8 w1f[4];
    #pragma unroll
    for (int q = 0; q < 4; ++q) {
        const int n = w * 64 + q * 16 + l15;
        #pragma unroll
        for (int j = 0; j < 8; ++j) {
            const int k = lg * 8 + j;
            float v = (k < NF) ? W1[k * HID + n] : (k == NF ? b1[n] : 0.0f);
            w1f[q][j] = (short)f2bf(v);
        }
    }
    float b3r[4];
    #pragma unroll
    for (int r = 0; r < 4; ++r) {
        const int s = lg * 4 + r;
        b3r[r] = (s < NS) ? b3[s] : 0.0f;
    }
    for (int i = tid; i < HID; i += 256) b2s[i] = b2[i];
    for (int i = tid; i < 16 * HID; i += 256) {
        const int s = i & 15, k = i >> 4;
        w3t[s][k] = (s < NS) ? f2bf(W3[k * NS + s]) : (unsigned short)0;
    }
    // net-in rows: x[b][0][0..8], bias-one at k=9, zeros above
    if (tid < BT) {
        const float* xp = &x[(b0 + tid) * (HS * NF)];
        #pragma unroll
        for (int k = 0; k < NIP; ++k) nibf[tid][k] = 0;
        #pragma unroll
        for (int f = 0; f < NF; ++f) nibf[tid][f] = f2bf(xp[f]);
        nibf[tid][NF] = f2bf(1.0f);
    }
    // master state in registers of waves 0,1: lane (l15,lg) owns b=w*16+l15, s=lg*4+r
    float st[4] = {0.f, 0.f, 0.f, 0.f};
    if (w < 2) {
        const int b = w * 16 + l15;
        #pragma unroll
        for (int r = 0; r < 4; ++r) {
            const int s = lg * 4 + r;
            if (s < NS) st[r] = x[(b0 + b) * (HS * NF) + NC + s];
        }
    }
    __syncthreads();

    for (int t = 0; t < HS; ++t) {
        // ---------- P1: h1 = tanh([ni,1] @ W1') via MFMA ----------
        f32x4 a1[4][2];
        #pragma unroll
        for (int q = 0; q < 4; ++q) { a1[q][0] = {0,0,0,0}; a1[q][1] = {0,0,0,0}; }
        #pragma unroll
        for (int bt = 0; bt < 2; ++bt) {
            short8 nf = *reinterpret_cast<const short8*>(&nibf[bt * 16 + l15][lg * 8]);
            #pragma unroll
            for (int q = 0; q < 4; ++q)
                a1[q][bt] = __builtin_amdgcn_mfma_f32_16x16x32_bf16(w1f[q], nf, a1[q][bt], 0, 0, 0);
        }
        #pragma unroll
        for (int q = 0; q < 4; ++q)
            #pragma unroll
            for (int bt = 0; bt < 2; ++bt) {
                unsigned int lo = cvt_pk_bf16(fast_tanh(a1[q][bt][0]), fast_tanh(a1[q][bt][1]));
                unsigned int hi = cvt_pk_bf16(fast_tanh(a1[q][bt][2]), fast_tanh(a1[q][bt][3]));
                uint2 pk; pk.x = lo; pk.y = hi;
                *reinterpret_cast<uint2*>(&hA[bt * 16 + l15][w * 64 + q * 16 + lg * 4]) = pk;
            }
        __syncthreads();   // S1: h1 ready

        // ---------- P2: h2 = tanh(h1 @ W2 + b2) via MFMA (b2 folded into init) ----------
        f32x4 acc[4][2];
        #pragma unroll
        for (int q = 0; q < 4; ++q) {
            const float4 bv = *reinterpret_cast<const float4*>(&b2s[w * 64 + q * 16 + lg * 4]);
            f32x4 bi; bi[0] = bv.x; bi[1] = bv.y; bi[2] = bv.z; bi[3] = bv.w;
            acc[q][0] = bi; acc[q][1] = bi;
        }
        #pragma unroll
        for (int kb = 0; kb < 8; ++kb) {
            short8 h0 = *reinterpret_cast<const short8*>(&hA[l15][kb * 32 + lg * 8]);
            short8 h1v = *reinterpret_cast<const short8*>(&hA[16 + l15][kb * 32 + lg * 8]);
            #pragma unroll
            for (int q = 0; q < 4; ++q) {
                acc[q][0] = __builtin_amdgcn_mfma_f32_16x16x32_bf16(w2f[q][kb], h0, acc[q][0], 0, 0, 0);
                acc[q][1] = __builtin_amdgcn_mfma_f32_16x16x32_bf16(w2f[q][kb], h1v, acc[q][1], 0, 0, 0);
            }
        }
        #pragma unroll
        for (int q = 0; q < 4; ++q) {
            #pragma unroll
            for (int bt = 0; bt < 2; ++bt) {
                unsigned int lo = cvt_pk_bf16(fast_tanh(acc[q][bt][0]),
                                              fast_tanh(acc[q][bt][1]));
                unsigned int hi = cvt_pk_bf16(fast_tanh(acc[q][bt][2]),
                                              fast_tanh(acc[q][bt][3]));
                uint2 pk; pk.x = lo; pk.y = hi;
                *reinterpret_cast<uint2*>(&hB[bt * 16 + l15][w * 64 + q * 16 + lg * 4]) = pk;
            }
        }
        __syncthreads();   // S2: h2 ready, h1 free

        // ---------- P3: d = h2 @ W3 + b3; state += DT*d ----------
        if (w < 2) {
            f32x4 a3 = {0.f, 0.f, 0.f, 0.f};
            #pragma unroll
            for (int kb = 0; kb < 8; ++kb) {
                short8 hv = *reinterpret_cast<const short8*>(&hB[w * 16 + l15][kb * 32 + lg * 8]);
                short8 wf = *reinterpret_cast<const short8*>(&w3t[l15][kb * 32 + lg * 8]);
                a3 = __builtin_amdgcn_mfma_f32_16x16x32_bf16(wf, hv, a3, 0, 0, 0);
            }
            const int b = w * 16 + l15;
            #pragma unroll
            for (int r = 0; r < 4; ++r) {
                const int s = lg * 4 + r;
                if (s < NS) {
                    float nsv = st[r] + DT_C * (a3[r] + b3r[r]);
                    st[r] = nsv;
                    nibf[b][NC + s] = f2bf(nsv);
                    out[(b0 + b) * (HS * NS) + t * NS + s] = nsv;
                }
            }
        } else if (w == 2) {
            // next-step controls -> nibf[b][0..1] (bf16)
            if (t + 1 < HS) {
                const int b = lane & 31, c = lane >> 5;
                nibf[b][c] = f2bf(x[(b0 + b) * (HS * NF) + (t + 1) * NF + c]);
            }
        }
        __syncthreads();   // S3: state/controls ready for next P1
    }
}

extern "C" void kernel_launch(void* const* d_in, const int* in_sizes, int n_in,
                              void* d_out, int out_size, void* d_ws, size_t ws_size,
                              hipStream_t stream) {
    const float* x  = (const float*)d_in[0];
    const float* W1 = (const float*)d_in[1];
    const float* b1 = (const float*)d_in[2];
    const float* W2 = (const float*)d_in[3];
    const float* b2 = (const float*)d_in[4];
    const float* W3 = (const float*)d_in[5];
    const float* b3 = (const float*)d_in[6];
    float* out = (float*)d_out;

    const int B = in_sizes[0] / (HS * NF);   // 32768
    dim3 grid(B / BT), block(256);
    hipLaunchKernelGGL(rollout_mfma3, grid, block, 0, stream,
                       x, W1, b1, W2, b2, W3, b3, out);
}

// Round 6
// 572.512 us; speedup vs baseline: 8.8466x; 1.0333x over previous
//
#include <hip/hip_runtime.h>
#include <hip/hip_bf16.h>

constexpr int HID = 256;
constexpr int NS = 7, NC = 2, NF = 9, HS = 50;
constexpr int BT  = 32;    // batch rows per block
constexpr int ROW = 264;   // bf16 row pitch for h buffers / w3t (528 B)
constexpr int NIP = 40;    // ni_bf row pitch in shorts (80 B, 16B-aligned)
constexpr float DT_C = 0.02f;

using short8 = __attribute__((ext_vector_type(8))) short;
using f32x4  = __attribute__((ext_vector_type(4))) float;

__device__ __forceinline__ unsigned short f2bf(float f) {
    unsigned int u = __float_as_uint(f);
    return (unsigned short)((u + 0x7FFFu + ((u >> 16) & 1u)) >> 16);   // RNE
}
__device__ __forceinline__ unsigned int pk2(float lo, float hi) {
    // compiler-schedulable packed bf16 convert (T12/m240: no inline asm here)
    __hip_bfloat162 h = __float22bfloat162_rn(make_float2(lo, hi));
    return *reinterpret_cast<unsigned int*>(&h);
}
__device__ __forceinline__ float fast_tanh(float x) {
    float e = __expf(2.0f * x);
    return 1.0f - __fdividef(2.0f, e + 1.0f);
}

__global__ __launch_bounds__(512, 4)
void rollout_mfma4(const float* __restrict__ x,
                   const float* __restrict__ W1, const float* __restrict__ b1,
                   const float* __restrict__ W2, const float* __restrict__ b2,
                   const float* __restrict__ W3, const float* __restrict__ b3,
                   float* __restrict__ out)
{
    __shared__ __align__(16) unsigned short hA[BT][ROW];    // h1
    __shared__ __align__(16) unsigned short hB[BT][ROW];    // h2
    __shared__ __align__(16) unsigned short w3t[16][ROW];   // W3^T, cols>=7 zero
    __shared__ __align__(16) unsigned short nibf[BT][NIP];  // [u0,u1,s0..6,1.0,0...]
    __shared__ __align__(16) float b2s[HID];

    const int tid  = threadIdx.x;
    const int w    = tid >> 6;        // wave 0..7, owns cols [w*32, w*32+32)
    const int lane = tid & 63;
    const int l15  = lane & 15;
    const int lg   = lane >> 4;
    const int b0   = blockIdx.x * BT;

    // ---- one-time: W2^T A-fragments (k = kb*32+lg*8+j, n = w*32+q*16+l15) ----
    short8 w2f[2][8];
    #pragma unroll
    for (int q = 0; q < 2; ++q) {
        const int n = w * 32 + q * 16 + l15;
        #pragma unroll
        for (int kb = 0; kb < 8; ++kb)
            #pragma unroll
            for (int j = 0; j < 8; ++j)
                w2f[q][kb][j] = (short)f2bf(W2[(kb * 32 + lg * 8 + j) * HID + n]);
    }
    // W1' A-fragments: rows 0..8 = W1, row 9 = b1 (bias via k), rows 10..31 = 0
    short8 w1f[2];
    #pragma unroll
    for (int q = 0; q < 2; ++q) {
        const int n = w * 32 + q * 16 + l15;
        #pragma unroll
        for (int j = 0; j < 8; ++j) {
            const int k = lg * 8 + j;
            float v = (k < NF) ? W1[k * HID + n] : (k == NF ? b1[n] : 0.0f);
            w1f[q][j] = (short)f2bf(v);
        }
    }
    float b3r[4];
    #pragma unroll
    for (int r = 0; r < 4; ++r) {
        const int s = lg * 4 + r;
        b3r[r] = (s < NS) ? b3[s] : 0.0f;
    }
    for (int i = tid; i < HID; i += 512) b2s[i] = b2[i];
    for (int i = tid; i < 16 * HID; i += 512) {
        const int s = i & 15, k = i >> 4;
        w3t[s][k] = (s < NS) ? f2bf(W3[k * NS + s]) : (unsigned short)0;
    }
    // net-in rows: x[b][0][0..8], bias-one at k=9, zeros above
    if (tid < BT) {
        const float* xp = &x[(b0 + tid) * (HS * NF)];
        #pragma unroll
        for (int k = 0; k < NIP; ++k) nibf[tid][k] = 0;
        #pragma unroll
        for (int f = 0; f < NF; ++f) nibf[tid][f] = f2bf(xp[f]);
        nibf[tid][NF] = f2bf(1.0f);
    }
    // master state in registers of waves 0,1: lane (l15,lg) owns b=w*16+l15, s=lg*4+r
    float st[4] = {0.f, 0.f, 0.f, 0.f};
    if (w < 2) {
        const int b = w * 16 + l15;
        #pragma unroll
        for (int r = 0; r < 4; ++r) {
            const int s = lg * 4 + r;
            if (s < NS) st[r] = x[(b0 + b) * (HS * NF) + NC + s];
        }
    }
    __syncthreads();

    for (int t = 0; t < HS; ++t) {
        // ---------- P1: h1 = tanh([ni,1] @ W1') via MFMA ----------
        f32x4 a1[2][2];
        #pragma unroll
        for (int q = 0; q < 2; ++q) { a1[q][0] = {0,0,0,0}; a1[q][1] = {0,0,0,0}; }
        #pragma unroll
        for (int bt = 0; bt < 2; ++bt) {
            short8 nf = *reinterpret_cast<const short8*>(&nibf[bt * 16 + l15][lg * 8]);
            #pragma unroll
            for (int q = 0; q < 2; ++q)
                a1[q][bt] = __builtin_amdgcn_mfma_f32_16x16x32_bf16(w1f[q], nf, a1[q][bt], 0, 0, 0);
        }
        #pragma unroll
        for (int q = 0; q < 2; ++q)
            #pragma unroll
            for (int bt = 0; bt < 2; ++bt) {
                uint2 pk;
                pk.x = pk2(fast_tanh(a1[q][bt][0]), fast_tanh(a1[q][bt][1]));
                pk.y = pk2(fast_tanh(a1[q][bt][2]), fast_tanh(a1[q][bt][3]));
                *reinterpret_cast<uint2*>(&hA[bt * 16 + l15][w * 32 + q * 16 + lg * 4]) = pk;
            }
        __syncthreads();   // S1: h1 ready

        // ---------- P2: h2 = tanh(h1 @ W2 + b2) via MFMA (b2 in acc init) ----------
        f32x4 acc[2][2];
        #pragma unroll
        for (int q = 0; q < 2; ++q) {
            const float4 bv = *reinterpret_cast<const float4*>(&b2s[w * 32 + q * 16 + lg * 4]);
            f32x4 bi; bi[0] = bv.x; bi[1] = bv.y; bi[2] = bv.z; bi[3] = bv.w;
            acc[q][0] = bi; acc[q][1] = bi;
        }
        #pragma unroll
        for (int kb = 0; kb < 8; ++kb) {
            short8 h0  = *reinterpret_cast<const short8*>(&hA[l15][kb * 32 + lg * 8]);
            short8 h1v = *reinterpret_cast<const short8*>(&hA[16 + l15][kb * 32 + lg * 8]);
            #pragma unroll
            for (int q = 0; q < 2; ++q) {
                acc[q][0] = __builtin_amdgcn_mfma_f32_16x16x32_bf16(w2f[q][kb], h0,  acc[q][0], 0, 0, 0);
                acc[q][1] = __builtin_amdgcn_mfma_f32_16x16x32_bf16(w2f[q][kb], h1v, acc[q][1], 0, 0, 0);
            }
        }
        #pragma unroll
        for (int q = 0; q < 2; ++q)
            #pragma unroll
            for (int bt = 0; bt < 2; ++bt) {
                uint2 pk;
                pk.x = pk2(fast_tanh(acc[q][bt][0]), fast_tanh(acc[q][bt][1]));
                pk.y = pk2(fast_tanh(acc[q][bt][2]), fast_tanh(acc[q][bt][3]));
                *reinterpret_cast<uint2*>(&hB[bt * 16 + l15][w * 32 + q * 16 + lg * 4]) = pk;
            }
        __syncthreads();   // S2: h2 ready, h1 free

        // ---------- P3: d = h2 @ W3 + b3; state += DT*d (waves 0,1) ----------
        if (w < 2) {
            f32x4 a3 = {0.f, 0.f, 0.f, 0.f};
            #pragma unroll
            for (int kb = 0; kb < 8; ++kb) {
                short8 hv = *reinterpret_cast<const short8*>(&hB[w * 16 + l15][kb * 32 + lg * 8]);
                short8 wf = *reinterpret_cast<const short8*>(&w3t[l15][kb * 32 + lg * 8]);
                a3 = __builtin_amdgcn_mfma_f32_16x16x32_bf16(wf, hv, a3, 0, 0, 0);
            }
            const int b = w * 16 + l15;
            #pragma unroll
            for (int r = 0; r < 4; ++r) {
                const int s = lg * 4 + r;
                if (s < NS) {
                    float nsv = st[r] + DT_C * (a3[r] + b3r[r]);
                    st[r] = nsv;
                    nibf[b][NC + s] = f2bf(nsv);
                    out[(b0 + b) * (HS * NS) + t * NS + s] = nsv;
                }
            }
        } else if (w == 2) {
            // next-step controls -> nibf[b][0..1] (bf16)
            if (t + 1 < HS) {
                const int b = lane & 31, c = lane >> 5;
                nibf[b][c] = f2bf(x[(b0 + b) * (HS * NF) + (t + 1) * NF + c]);
            }
        }
        __syncthreads();   // S3: state/controls ready for next P1
    }
}

extern "C" void kernel_launch(void* const* d_in, const int* in_sizes, int n_in,
                              void* d_out, int out_size, void* d_ws, size_t ws_size,
                              hipStream_t stream) {
    const float* x  = (const float*)d_in[0];
    const float* W1 = (const float*)d_in[1];
    const float* b1 = (const float*)d_in[2];
    const float* W2 = (const float*)d_in[3];
    const float* b2 = (const float*)d_in[4];
    const float* W3 = (const float*)d_in[5];
    const float* b3 = (const float*)d_in[6];
    float* out = (float*)d_out;

    const int B = in_sizes[0] / (HS * NF);   // 32768
    dim3 grid(B / BT), block(512);
    hipLaunchKernelGGL(rollout_mfma4, grid, block, 0, stream,
                       x, W1, b1, W2, b2, W3, b3, out);
}

// Round 8
// 413.135 us; speedup vs baseline: 12.2594x; 1.3858x over previous
//
#include <hip/hip_runtime.h>
#include <hip/hip_bf16.h>

constexpr int HID = 256;
constexpr int NS = 7, NC = 2, NF = 9, HS = 50;
constexpr int BT  = 32;    // batch rows per block
constexpr int ROW = 264;   // bf16 row pitch for h buffers / w3t (528 B)
constexpr int NIP = 40;    // ni_bf row pitch in shorts (80 B, 16B-aligned)
constexpr float DT_C = 0.02f;

using short8 = __attribute__((ext_vector_type(8))) short;
using f32x4  = __attribute__((ext_vector_type(4))) float;

__device__ __forceinline__ unsigned short f2bf(float f) {
    unsigned int u = __float_as_uint(f);
    return (unsigned short)((u + 0x7FFFu + ((u >> 16) & 1u)) >> 16);   // RNE
}
__device__ __forceinline__ unsigned int pk2(float lo, float hi) {
    // compiler-schedulable packed bf16 convert
    __hip_bfloat162 h = __float22bfloat162_rn(make_float2(lo, hi));
    return *reinterpret_cast<unsigned int*>(&h);
}
__device__ __forceinline__ float fast_tanh(float x) {
    // tanh(x) = 1 - 2/(e^{2x}+1); v_rcp_f32 forced via builtin (no IEEE div seq).
    // 4 VALU + 2 trans. inf-safe: e=inf -> rcp=0 -> 1; e=0 -> -1.
    float e = __expf(2.0f * x);
    return fmaf(-2.0f, __builtin_amdgcn_rcpf(e + 1.0f), 1.0f);
}

__global__ __launch_bounds__(512, 4)
void rollout_mfma5(const float* __restrict__ x,
                   const float* __restrict__ W1, const float* __restrict__ b1,
                   const float* __restrict__ W2, const float* __restrict__ b2,
                   const float* __restrict__ W3, const float* __restrict__ b3,
                   float* __restrict__ out)
{
    __shared__ __align__(16) unsigned short hA[BT][ROW];    // h1
    __shared__ __align__(16) unsigned short hB[BT][ROW];    // h2
    __shared__ __align__(16) unsigned short w3t[16][ROW];   // W3^T, cols>=7 zero
    __shared__ __align__(16) unsigned short nibf[BT][NIP];  // [u0,u1,s0..6,1.0,0...]
    __shared__ __align__(16) float b2s[HID];

    const int tid  = threadIdx.x;
    const int w    = tid >> 6;        // wave 0..7, owns cols [w*32, w*32+32)
    const int lane = tid & 63;
    const int l15  = lane & 15;
    const int lg   = lane >> 4;
    const int b0   = blockIdx.x * BT;

    // ---- one-time: W2^T A-fragments (k = kb*32+lg*8+j, n = w*32+q*16+l15) ----
    short8 w2f[2][8];
    #pragma unroll
    for (int q = 0; q < 2; ++q) {
        const int n = w * 32 + q * 16 + l15;
        #pragma unroll
        for (int kb = 0; kb < 8; ++kb)
            #pragma unroll
            for (int j = 0; j < 8; ++j)
                w2f[q][kb][j] = (short)f2bf(W2[(kb * 32 + lg * 8 + j) * HID + n]);
    }
    // W1' A-fragments: rows 0..8 = W1, row 9 = b1 (bias via k), rows 10..31 = 0
    short8 w1f[2];
    #pragma unroll
    for (int q = 0; q < 2; ++q) {
        const int n = w * 32 + q * 16 + l15;
        #pragma unroll
        for (int j = 0; j < 8; ++j) {
            const int k = lg * 8 + j;
            float v = (k < NF) ? W1[k * HID + n] : (k == NF ? b1[n] : 0.0f);
            w1f[q][j] = (short)f2bf(v);
        }
    }
    float b3r[4];
    #pragma unroll
    for (int r = 0; r < 4; ++r) {
        const int s = lg * 4 + r;
        b3r[r] = (s < NS) ? b3[s] : 0.0f;
    }
    for (int i = tid; i < HID; i += 512) b2s[i] = b2[i];
    for (int i = tid; i < 16 * HID; i += 512) {
        const int s = i & 15, k = i >> 4;
        w3t[s][k] = (s < NS) ? f2bf(W3[k * NS + s]) : (unsigned short)0;
    }
    // net-in rows: x[b][0][0..8], bias-one at k=9, zeros above
    if (tid < BT) {
        const float* xp = &x[(b0 + tid) * (HS * NF)];
        #pragma unroll
        for (int k = 0; k < NIP; ++k) nibf[tid][k] = 0;
        #pragma unroll
        for (int f = 0; f < NF; ++f) nibf[tid][f] = f2bf(xp[f]);
        nibf[tid][NF] = f2bf(1.0f);
    }
    // master state in registers of waves 0,1: lane (l15,lg) owns b=w*16+l15, s=lg*4+r
    float st[4] = {0.f, 0.f, 0.f, 0.f};
    if (w < 2) {
        const int b = w * 16 + l15;
        #pragma unroll
        for (int r = 0; r < 4; ++r) {
            const int s = lg * 4 + r;
            if (s < NS) st[r] = x[(b0 + b) * (HS * NF) + NC + s];
        }
    }
    __syncthreads();

    for (int t = 0; t < HS; ++t) {
        // ---------- P1: h1 = tanh([ni,1] @ W1') via MFMA ----------
        f32x4 a1[2][2];
        #pragma unroll
        for (int q = 0; q < 2; ++q) { a1[q][0] = {0,0,0,0}; a1[q][1] = {0,0,0,0}; }
        #pragma unroll
        for (int bt = 0; bt < 2; ++bt) {
            short8 nf = *reinterpret_cast<const short8*>(&nibf[bt * 16 + l15][lg * 8]);
            #pragma unroll
            for (int q = 0; q < 2; ++q)
                a1[q][bt] = __builtin_amdgcn_mfma_f32_16x16x32_bf16(w1f[q], nf, a1[q][bt], 0, 0, 0);
        }
        #pragma unroll
        for (int q = 0; q < 2; ++q)
            #pragma unroll
            for (int bt = 0; bt < 2; ++bt) {
                uint2 pk;
                pk.x = pk2(fast_tanh(a1[q][bt][0]), fast_tanh(a1[q][bt][1]));
                pk.y = pk2(fast_tanh(a1[q][bt][2]), fast_tanh(a1[q][bt][3]));
                *reinterpret_cast<uint2*>(&hA[bt * 16 + l15][w * 32 + q * 16 + lg * 4]) = pk;
            }
        __syncthreads();   // S1: h1 ready

        // ---------- P2: h2 = tanh(h1 @ W2 + b2) via MFMA (b2 in acc init) ----------
        f32x4 acc[2][2];
        #pragma unroll
        for (int q = 0; q < 2; ++q) {
            const float4 bv = *reinterpret_cast<const float4*>(&b2s[w * 32 + q * 16 + lg * 4]);
            f32x4 bi; bi[0] = bv.x; bi[1] = bv.y; bi[2] = bv.z; bi[3] = bv.w;
            acc[q][0] = bi; acc[q][1] = bi;
        }
        #pragma unroll
        for (int kb = 0; kb < 8; ++kb) {
            short8 h0  = *reinterpret_cast<const short8*>(&hA[l15][kb * 32 + lg * 8]);
            short8 h1v = *reinterpret_cast<const short8*>(&hA[16 + l15][kb * 32 + lg * 8]);
            #pragma unroll
            for (int q = 0; q < 2; ++q) {
                acc[q][0] = __builtin_amdgcn_mfma_f32_16x16x32_bf16(w2f[q][kb], h0,  acc[q][0], 0, 0, 0);
                acc[q][1] = __builtin_amdgcn_mfma_f32_16x16x32_bf16(w2f[q][kb], h1v, acc[q][1], 0, 0, 0);
            }
        }
        #pragma unroll
        for (int q = 0; q < 2; ++q)
            #pragma unroll
            for (int bt = 0; bt < 2; ++bt) {
                uint2 pk;
                pk.x = pk2(fast_tanh(acc[q][bt][0]), fast_tanh(acc[q][bt][1]));
                pk.y = pk2(fast_tanh(acc[q][bt][2]), fast_tanh(acc[q][bt][3]));
                *reinterpret_cast<uint2*>(&hB[bt * 16 + l15][w * 32 + q * 16 + lg * 4]) = pk;
            }
        __syncthreads();   // S2: h2 ready, h1 free

        // ---------- P3: d = h2 @ W3 + b3; state += DT*d (waves 0,1) ----------
        if (w < 2) {
            f32x4 a3 = {0.f, 0.f, 0.f, 0.f};
            #pragma unroll
            for (int kb = 0; kb < 8; ++kb) {
                short8 hv = *reinterpret_cast<const short8*>(&hB[w * 16 + l15][kb * 32 + lg * 8]);
                short8 wf = *reinterpret_cast<const short8*>(&w3t[l15][kb * 32 + lg * 8]);
                a3 = __builtin_amdgcn_mfma_f32_16x16x32_bf16(wf, hv, a3, 0, 0, 0);
            }
            const int b = w * 16 + l15;
            float nsv[4];
            #pragma unroll
            for (int r = 0; r < 4; ++r) nsv[r] = st[r] + DT_C * (a3[r] + b3r[r]);
            if (lg == 0) {
                // s = 0..3 -> nibf shorts [2..5] (bytes 4..11, 4B-aligned)
                st[0] = nsv[0]; st[1] = nsv[1]; st[2] = nsv[2]; st[3] = nsv[3];
                *reinterpret_cast<unsigned int*>(&nibf[b][2]) = pk2(nsv[0], nsv[1]);
                *reinterpret_cast<unsigned int*>(&nibf[b][4]) = pk2(nsv[2], nsv[3]);
                const int obase = (b0 + b) * (HS * NS) + t * NS;
                out[obase + 0] = nsv[0];
                out[obase + 1] = nsv[1];
                out[obase + 2] = nsv[2];
                out[obase + 3] = nsv[3];
            } else if (lg == 1) {
                // s = 4..6 -> nibf shorts [6..8]
                st[0] = nsv[0]; st[1] = nsv[1]; st[2] = nsv[2];
                *reinterpret_cast<unsigned int*>(&nibf[b][6]) = pk2(nsv[0], nsv[1]);
                nibf[b][8] = (unsigned short)pk2(nsv[2], nsv[2]);
                const int obase = (b0 + b) * (HS * NS) + t * NS;
                out[obase + 4] = nsv[0];
                out[obase + 5] = nsv[1];
                out[obase + 6] = nsv[2];
            }
        } else if (w == 2) {
            // next-step controls -> nibf[b][0..1] (bf16)
            if (t + 1 < HS) {
                const int b = lane & 31, c = lane >> 5;
                nibf[b][c] = f2bf(x[(b0 + b) * (HS * NF) + (t + 1) * NF + c]);
            }
        }
        __syncthreads();   // S3: state/controls ready for next P1
    }
}

extern "C" void kernel_launch(void* const* d_in, const int* in_sizes, int n_in,
                              void* d_out, int out_size, void* d_ws, size_t ws_size,
                              hipStream_t stream) {
    const float* x  = (const float*)d_in[0];
    const float* W1 = (const float*)d_in[1];
    const float* b1 = (const float*)d_in[2];
    const float* W2 = (const float*)d_in[3];
    const float* b2 = (const float*)d_in[4];
    const float* W3 = (const float*)d_in[5];
    const float* b3 = (const float*)d_in[6];
    float* out = (float*)d_out;

    const int B = in_sizes[0] / (HS * NF);   // 32768
    dim3 grid(B / BT), block(512);
    hipLaunchKernelGGL(rollout_mfma5, grid, block, 0, stream,
                       x, W1, b1, W2, b2, W3, b3, out);
}